// Round 1
// baseline (1674.763 us; speedup 1.0000x reference)
//
#include <hip/hip_runtime.h>

// GNN forward for MI355X. Strategy:
//  - counting-sort edges by receiver (hist/scan/scatter) once per call
//  - edge first-layer decomposed: P_s = h@Ws, P_r = h@Wr (node-level GEMMs),
//    per-edge: t = P_s[s]+P_r[r]+xe@We+b1 (xe part via K=16-padded MFMA)
//  - edge second GEMM via mfma_f32_16x16x32_bf16, fused segmented-reduce
//    (sorted-by-receiver) -> few fp32 atomics per tile into aggr
//  - node MLPs via generic bf16-MFMA GEMM kernel (weights staged in LDS)
//  - pooling exploits sorted `batch` (binary search per graph)

typedef short bf16x8 __attribute__((ext_vector_type(8)));
typedef float f32x4 __attribute__((ext_vector_type(4)));

union U8 { bf16x8 v; unsigned short u[8]; };

__device__ __forceinline__ float bf2f(unsigned short u) {
    union { unsigned int i; float f; } x; x.i = ((unsigned int)u) << 16; return x.f;
}
__device__ __forceinline__ unsigned short f2bf(float f) {
    union { float f; unsigned int i; } x; x.f = f;
    unsigned int r = x.i + 0x7FFFu + ((x.i >> 16) & 1u);
    return (unsigned short)(r >> 16);
}
__device__ __forceinline__ float siluf(float x) { return x / (1.0f + __expf(-x)); }

// ---------------- setup: counting sort by receiver ----------------
__global__ void k_hist(const int* __restrict__ recv, int* __restrict__ counts, int E) {
    int i = blockIdx.x * 256 + threadIdx.x;
    if (i < E) atomicAdd(&counts[recv[i]], 1);
}

__global__ void k_scan(const int* __restrict__ counts, int* __restrict__ offsets, int n) {
    __shared__ int buf[1024];
    __shared__ int carry;
    if (threadIdx.x == 0) carry = 0;
    __syncthreads();
    for (int base = 0; base < n; base += 1024) {
        int i = base + (int)threadIdx.x;
        int v = (i < n) ? counts[i] : 0;
        buf[threadIdx.x] = v;
        __syncthreads();
        for (int off = 1; off < 1024; off <<= 1) {
            int t = 0;
            if ((int)threadIdx.x >= off) t = buf[threadIdx.x - off];
            __syncthreads();
            if ((int)threadIdx.x >= off) buf[threadIdx.x] += t;
            __syncthreads();
        }
        if (i < n) offsets[i] = carry + buf[threadIdx.x] - v;
        __syncthreads();
        if (threadIdx.x == 0) carry += buf[1023];
        __syncthreads();
    }
    if (threadIdx.x == 0) offsets[n] = carry;
}

__global__ void k_scatter(const int* __restrict__ send, const int* __restrict__ recv,
                          const int* __restrict__ offsets, int* __restrict__ cursor,
                          int* __restrict__ ss, int* __restrict__ sr,
                          int* __restrict__ perm, int E) {
    int i = blockIdx.x * 256 + threadIdx.x;
    if (i < E) {
        int r = recv[i];
        int pos = offsets[r] + atomicAdd(&cursor[r], 1);
        ss[pos] = send[i];
        sr[pos] = r;
        perm[pos] = i;
    }
}

__global__ void k_permute_xe(const float* __restrict__ xe, const int* __restrict__ perm,
                             unsigned short* __restrict__ out, int E) {
    int t = blockIdx.x * 256 + threadIdx.x;
    if (t < E * 4) {
        int pos = t >> 2, q = t & 3;
        int e = perm[pos];
        float4 v = *(const float4*)(xe + (size_t)e * 16 + q * 4);
        ushort4 o;
        o.x = f2bf(v.x); o.y = f2bf(v.y); o.z = f2bf(v.z); o.w = f2bf(v.w);
        *(ushort4*)(out + (size_t)pos * 16 + q * 4) = o;
    }
}

// ---------------- embed stage 1 (K=16, VALU) ----------------
__global__ __launch_bounds__(256) void k_embed1(const float* __restrict__ x,
                                                const float* __restrict__ w1,
                                                const float* __restrict__ b1,
                                                unsigned short* __restrict__ out, int N) {
    int idx = blockIdx.x * 256 + threadIdx.x;
    int n = idx >> 6, lane = idx & 63;
    if (n >= N) return;
    const float* xr = x + (size_t)n * 16;
    float xv[16];
#pragma unroll
    for (int k = 0; k < 16; k += 4) {
        float4 v = *(const float4*)(xr + k);
        xv[k] = v.x; xv[k + 1] = v.y; xv[k + 2] = v.z; xv[k + 3] = v.w;
    }
    int c0 = lane * 2;
    float a0 = b1[c0], a1 = b1[c0 + 1];
#pragma unroll
    for (int k = 0; k < 16; ++k) {
        float2 w = *(const float2*)(w1 + k * 128 + c0);
        a0 += xv[k] * w.x; a1 += xv[k] * w.y;
    }
    unsigned int pk = (unsigned int)f2bf(siluf(a0)) | ((unsigned int)f2bf(siluf(a1)) << 16);
    *(unsigned int*)(out + (size_t)n * 128 + c0) = pk;
}

// ---------------- generic node GEMM: out = act(A1@W1 [+ A2@W2] + b) ----------------
// A bf16 [M,128] (or A2f f32), W fp32 [128,128]; MFMA bf16, fp32 accum.
__global__ __launch_bounds__(256) void k_gemm128(
    const unsigned short* __restrict__ A1, const float* __restrict__ W1,
    const float* __restrict__ A2f, const float* __restrict__ W2,
    const float* __restrict__ bias, int M, int act,
    unsigned short* __restrict__ outB, float* __restrict__ outF) {
    __shared__ unsigned short sW[128 * 136];
    int tid = threadIdx.x, lane = tid & 63, w = tid >> 6;
    int r0 = blockIdx.x * 64 + w * 16;
    int colb = lane & 15, kg = lane >> 4;
    int row = r0 + colb;
    bool rv = row < M;
    f32x4 C[8];
#pragma unroll
    for (int cf = 0; cf < 8; ++cf) C[cf] = (f32x4){0.f, 0.f, 0.f, 0.f};
    int npass = (W2 != nullptr) ? 2 : 1;
    for (int pass = 0; pass < npass; ++pass) {
        const float* W = pass ? W2 : W1;
        __syncthreads();
        for (int i = tid; i < 16384; i += 256) {
            int k = i >> 7, c = i & 127;
            sW[c * 136 + k] = f2bf(W[i]);
        }
        __syncthreads();
        bf16x8 A[4];
        if (pass == 0) {
#pragma unroll
            for (int ks = 0; ks < 4; ++ks) {
                if (rv) A[ks] = *(const bf16x8*)(A1 + (size_t)row * 128 + ks * 32 + kg * 8);
                else { U8 z; for (int i = 0; i < 8; ++i) z.u[i] = 0; A[ks] = z.v; }
            }
        } else {
#pragma unroll
            for (int ks = 0; ks < 4; ++ks) {
                U8 t;
                if (rv) {
                    const float* p = A2f + (size_t)row * 128 + ks * 32 + kg * 8;
#pragma unroll
                    for (int i = 0; i < 8; ++i) t.u[i] = f2bf(p[i]);
                } else {
                    for (int i = 0; i < 8; ++i) t.u[i] = 0;
                }
                A[ks] = t.v;
            }
        }
#pragma unroll
        for (int ks = 0; ks < 4; ++ks) {
#pragma unroll
            for (int cf = 0; cf < 8; ++cf) {
                bf16x8 B = *(const bf16x8*)(&sW[(colb + 16 * cf) * 136 + ks * 32 + kg * 8]);
                C[cf] = __builtin_amdgcn_mfma_f32_16x16x32_bf16(A[ks], B, C[cf], 0, 0, 0);
            }
        }
    }
    int rb = r0 + kg * 4;
#pragma unroll
    for (int cf = 0; cf < 8; ++cf) {
        int col = colb + 16 * cf;
        float bb = bias ? bias[col] : 0.f;
#pragma unroll
        for (int j = 0; j < 4; ++j) {
            int r = rb + j;
            if (r < M) {
                float v = C[cf][j] + bb;
                if (act) v = siluf(v);
                if (outB) outB[(size_t)r * 128 + col] = f2bf(v);
                else outF[(size_t)r * 128 + col] = v;
            }
        }
    }
}

// ---------------- fused edge kernel ----------------
// per 64-edge tile (sorted by receiver):
//   t = P_s[s] + P_r[r] + b1  (gather, fp32, stored bf16 in LDS)
//   t += xe @ We  (K=16-padded MFMA); u = silu(t)
//   msg = silu(u @ W2 + b2)   (MFMA, W2^T staged in LDS)
//   segmented reduce over sorted receivers -> few fp32 atomics into aggr
__global__ __launch_bounds__(256) void k_edge(
    const unsigned short* __restrict__ Ps, const unsigned short* __restrict__ Pr,
    const unsigned short* __restrict__ xes,
    const int* __restrict__ ssend, const int* __restrict__ srecv,
    const float* __restrict__ We, const float* __restrict__ b1,
    const float* __restrict__ W2, const float* __restrict__ b2,
    float* __restrict__ aggr, int E) {
    __shared__ unsigned short sW2[128 * 136];  // W2^T: [col][k], pad 8 -> 2-way-free b128 reads
    __shared__ unsigned short sT[64 * 136];    // t / u / msg tile, bf16
    __shared__ unsigned short sXe[64 * 16];
    __shared__ int sSid[64], sRid[64];
    int tid = threadIdx.x, lane = tid & 63, w = tid >> 6;
    int colb = lane & 15, kg = lane >> 4;

    for (int i = tid; i < 16384; i += 256) {
        int k = i >> 7, c = i & 127;
        sW2[c * 136 + k] = f2bf(W2[i]);
    }
    // We (16x128) B-fragments kept in registers, zero-padded to K=32
    bf16x8 WeB[8];
#pragma unroll
    for (int cf = 0; cf < 8; ++cf) {
        U8 t;
#pragma unroll
        for (int i = 0; i < 8; ++i) {
            int k = kg * 8 + i;
            t.u[i] = (k < 16) ? f2bf(We[k * 128 + colb + 16 * cf]) : (unsigned short)0;
        }
        WeB[cf] = t.v;
    }
    float b1v0 = b1[lane * 2], b1v1 = b1[lane * 2 + 1];
    float b2v[8];
#pragma unroll
    for (int cf = 0; cf < 8; ++cf) b2v[cf] = b2[colb + 16 * cf];
    __syncthreads();

    int ntiles = E >> 6;
    int R0 = w * 16;
    int rb = R0 + kg * 4;
    for (int tile = blockIdx.x; tile < ntiles; tile += gridDim.x) {
        int e0 = tile << 6;
        if (tid < 64) { sSid[tid] = ssend[e0 + tid]; sRid[tid] = srecv[e0 + tid]; }
        ((ushort4*)sXe)[tid] = ((const ushort4*)(xes + (size_t)e0 * 16))[tid];
        __syncthreads();
        // phase 1: gather P_s + P_r + b1 (row-wise, coalesced 4B/lane)
#pragma unroll 4
        for (int i = 0; i < 16; ++i) {
            int e = R0 + i;
            int s = sSid[e], r = sRid[e];
            unsigned int a = *(const unsigned int*)(Ps + (size_t)s * 128 + lane * 2);
            unsigned int b = *(const unsigned int*)(Pr + (size_t)r * 128 + lane * 2);
            float v0 = bf2f((unsigned short)(a & 0xffff)) + bf2f((unsigned short)(b & 0xffff)) + b1v0;
            float v1 = bf2f((unsigned short)(a >> 16)) + bf2f((unsigned short)(b >> 16)) + b1v1;
            *(unsigned int*)(sT + e * 136 + lane * 2) =
                (unsigned int)f2bf(v0) | ((unsigned int)f2bf(v1) << 16);
        }
        __syncthreads();
        // phase 2: xe@We via MFMA (K=16 zero-padded), add, silu, write back bf16
        bf16x8 Axe;
        if (kg < 2) Axe = *(const bf16x8*)(sXe + (R0 + colb) * 16 + kg * 8);
        else { U8 z; for (int i = 0; i < 8; ++i) z.u[i] = 0; Axe = z.v; }
        f32x4 xc[8];
#pragma unroll
        for (int cf = 0; cf < 8; ++cf) {
            f32x4 z = {0.f, 0.f, 0.f, 0.f};
            xc[cf] = __builtin_amdgcn_mfma_f32_16x16x32_bf16(Axe, WeB[cf], z, 0, 0, 0);
        }
#pragma unroll
        for (int cf = 0; cf < 8; ++cf) {
            int col = colb + 16 * cf;
#pragma unroll
            for (int j = 0; j < 4; ++j) {
                int row = rb + j;
                float v = bf2f(sT[row * 136 + col]) + xc[cf][j];
                sT[row * 136 + col] = f2bf(siluf(v));
            }
        }
        __syncthreads();
        // phase 3: msg = silu(u @ W2 + b2)
        bf16x8 A2[4];
#pragma unroll
        for (int ks = 0; ks < 4; ++ks)
            A2[ks] = *(const bf16x8*)(sT + (R0 + colb) * 136 + ks * 32 + kg * 8);
        f32x4 m[8];
#pragma unroll
        for (int cf = 0; cf < 8; ++cf) m[cf] = (f32x4){0.f, 0.f, 0.f, 0.f};
#pragma unroll
        for (int ks = 0; ks < 4; ++ks) {
#pragma unroll
            for (int cf = 0; cf < 8; ++cf) {
                bf16x8 B = *(const bf16x8*)(sW2 + (colb + 16 * cf) * 136 + ks * 32 + kg * 8);
                m[cf] = __builtin_amdgcn_mfma_f32_16x16x32_bf16(A2[ks], B, m[cf], 0, 0, 0);
            }
        }
#pragma unroll
        for (int cf = 0; cf < 8; ++cf) {
            int col = colb + 16 * cf;
#pragma unroll
            for (int j = 0; j < 4; ++j) {
                int row = rb + j;
                sT[row * 136 + col] = f2bf(siluf(m[cf][j] + b2v[cf]));
            }
        }
        __syncthreads();
        // phase 4: segmented reduce over sorted receivers -> fp32 atomics
        {
            int col = tid & 127, half = tid >> 7;
            int base = half * 32;
            float acc = 0.f;
            int prev = sRid[base];
            for (int rr = 0; rr < 32; ++rr) {
                int row = base + rr;
                int rid = sRid[row];
                if (rid != prev) {
                    atomicAdd(&aggr[(size_t)prev * 128 + col], acc);
                    acc = 0.f;
                    prev = rid;
                }
                acc += bf2f(sT[row * 136 + col]);
            }
            atomicAdd(&aggr[(size_t)prev * 128 + col], acc);
        }
        __syncthreads();
    }
}

// ---------------- pooling (batch sorted -> contiguous graph ranges) ----------------
__device__ __forceinline__ int lowerb(const int* a, int n, int v) {
    int lo = 0, hi = n;
    while (lo < hi) { int mid = (lo + hi) >> 1; if (a[mid] < v) lo = mid + 1; else hi = mid; }
    return lo;
}

__global__ __launch_bounds__(128) void k_pool(const float* __restrict__ hpr,
                                              const int* __restrict__ batch,
                                              float* __restrict__ pooled, int N) {
    __shared__ int s_lo, s_hi;
    int g = blockIdx.x;
    if (threadIdx.x == 0) { s_lo = lowerb(batch, N, g); s_hi = lowerb(batch, N, g + 1); }
    __syncthreads();
    int c = threadIdx.x;
    float acc = 0.f;
    for (int r = s_lo; r < s_hi; ++r) acc += hpr[(size_t)r * 128 + c];
    pooled[(size_t)g * 128 + c] = acc;
}

__global__ __launch_bounds__(128) void k_readout(const float* __restrict__ pooled,
                                                 const float* __restrict__ w1,
                                                 const float* __restrict__ b1,
                                                 const float* __restrict__ w2,
                                                 const float* __restrict__ b2,
                                                 float* __restrict__ out) {
    __shared__ float sp[128];
    __shared__ float sred[2];
    int g = blockIdx.x, t = threadIdx.x;
    sp[t] = pooled[(size_t)g * 128 + t];
    __syncthreads();
    float acc = b1[t];
    for (int k = 0; k < 128; ++k) acc += sp[k] * w1[k * 128 + t];
    float val = siluf(acc) * w2[t];
#pragma unroll
    for (int off = 32; off; off >>= 1) val += __shfl_down(val, off);
    if ((t & 63) == 0) sred[t >> 6] = val;
    __syncthreads();
    if (t == 0) out[g] = sred[0] + sred[1] + b2[0];
}

// ---------------- host launcher ----------------
extern "C" void kernel_launch(void* const* d_in, const int* in_sizes, int n_in,
                              void* d_out, int out_size, void* d_ws, size_t ws_size,
                              hipStream_t stream) {
    const float* x_nodes = (const float*)d_in[0];
    const float* x_edges = (const float*)d_in[1];
    const int* edge_index = (const int*)d_in[2];
    const int* batch = (const int*)d_in[3];
    const float* emb_w1 = (const float*)d_in[4];
    const float* emb_b1 = (const float*)d_in[5];
    const float* emb_w2 = (const float*)d_in[6];
    const float* emb_b2 = (const float*)d_in[7];
    const float* ew1 = (const float*)d_in[8];
    const float* eb1 = (const float*)d_in[9];
    const float* ew2 = (const float*)d_in[10];
    const float* eb2 = (const float*)d_in[11];
    const float* nw1 = (const float*)d_in[12];
    const float* nb1 = (const float*)d_in[13];
    const float* nw2 = (const float*)d_in[14];
    const float* nb2 = (const float*)d_in[15];
    const float* pr_w1 = (const float*)d_in[16];
    const float* pr_b1 = (const float*)d_in[17];
    const float* pr_w2 = (const float*)d_in[18];
    const float* pr_b2 = (const float*)d_in[19];
    const float* ro_w1 = (const float*)d_in[20];
    const float* ro_b1 = (const float*)d_in[21];
    const float* ro_w2 = (const float*)d_in[22];
    const float* ro_b2 = (const float*)d_in[23];

    const int N = in_sizes[0] / 16;
    const int E = in_sizes[1] / 16;
    const int G = 512;
    const int L = 4;

    // workspace carve-up (~139 MB)
    char* p = (char*)d_ws;
    auto alloc = [&](size_t bytes) {
        void* r = p;
        p += (bytes + 255) & ~(size_t)255;
        return r;
    };
    int* counts = (int*)alloc((size_t)N * 4);
    int* cursor = (int*)alloc((size_t)N * 4);
    int* offsets = (int*)alloc((size_t)(N + 1) * 4);
    int* ss = (int*)alloc((size_t)E * 4);
    int* sr = (int*)alloc((size_t)E * 4);
    int* perm = (int*)alloc((size_t)E * 4);
    unsigned short* xes = (unsigned short*)alloc((size_t)E * 16 * 2);
    unsigned short* h = (unsigned short*)alloc((size_t)N * 128 * 2);
    unsigned short* t0 = (unsigned short*)alloc((size_t)N * 128 * 2);
    unsigned short* Ps = (unsigned short*)alloc((size_t)N * 128 * 2);
    unsigned short* Pr = (unsigned short*)alloc((size_t)N * 128 * 2);
    float* aggr = (float*)alloc((size_t)N * 128 * 4);
    float* hpr = (float*)alloc((size_t)N * 128 * 4);
    float* pooled = (float*)alloc((size_t)G * 128 * 4);

    const int* send = edge_index;
    const int* recv = edge_index + E;

    // counting sort by receiver
    hipMemsetAsync(counts, 0, (size_t)N * 4, stream);
    hipMemsetAsync(cursor, 0, (size_t)N * 4, stream);
    k_hist<<<(E + 255) / 256, 256, 0, stream>>>(recv, counts, E);
    k_scan<<<1, 1024, 0, stream>>>(counts, offsets, N);
    k_scatter<<<(E + 255) / 256, 256, 0, stream>>>(send, recv, offsets, cursor, ss, sr, perm, E);
    k_permute_xe<<<(E * 4 + 255) / 256, 256, 0, stream>>>(x_edges, perm, xes, E);

    // embed
    k_embed1<<<(N * 64 + 255) / 256, 256, 0, stream>>>(x_nodes, emb_w1, emb_b1, t0, N);
    int gb = (N + 63) / 64;
    k_gemm128<<<gb, 256, 0, stream>>>(t0, emb_w2, nullptr, nullptr, emb_b2, N, 0, h, nullptr);

    for (int l = 0; l < L; ++l) {
        const float* ew1_l = ew1 + (size_t)l * 272 * 128;
        const float* ew2_l = ew2 + (size_t)l * 128 * 128;
        const float* nw1_l = nw1 + (size_t)l * 256 * 128;
        const float* nw2_l = nw2 + (size_t)l * 128 * 128;
        const float* eb1_l = eb1 + l * 128;
        const float* eb2_l = eb2 + l * 128;
        const float* nb1_l = nb1 + l * 128;
        const float* nb2_l = nb2 + l * 128;

        k_gemm128<<<gb, 256, 0, stream>>>(h, ew1_l, nullptr, nullptr, nullptr, N, 0, Ps, nullptr);
        k_gemm128<<<gb, 256, 0, stream>>>(h, ew1_l + 128 * 128, nullptr, nullptr, nullptr, N, 0, Pr, nullptr);
        hipMemsetAsync(aggr, 0, (size_t)N * 128 * 4, stream);
        k_edge<<<2048, 256, 0, stream>>>(Ps, Pr, xes, ss, sr, ew1_l + 256 * 128, eb1_l,
                                         ew2_l, eb2_l, aggr, E);
        k_gemm128<<<gb, 256, 0, stream>>>(h, nw1_l, aggr, nw1_l + 128 * 128, nb1_l, N, 1, t0, nullptr);
        k_gemm128<<<gb, 256, 0, stream>>>(t0, nw2_l, nullptr, nullptr, nb2_l, N, 0, h, nullptr);
    }

    // pre-readout + pooling + readout
    k_gemm128<<<gb, 256, 0, stream>>>(h, pr_w1, nullptr, nullptr, pr_b1, N, 1, t0, nullptr);
    k_gemm128<<<gb, 256, 0, stream>>>(t0, pr_w2, nullptr, nullptr, pr_b2, N, 0, nullptr, hpr);
    k_pool<<<G, 128, 0, stream>>>(hpr, batch, pooled, N);
    k_readout<<<G, 128, 0, stream>>>(pooled, ro_w1, ro_b1, ro_w2, ro_b2, (float*)d_out);
}